// Round 1
// baseline (7925.476 us; speedup 1.0000x reference)
//
#include <hip/hip_runtime.h>
#include <hip/hip_bf16.h>

#define B_ 64
#define T_ 1024
#define E_ 256
#define H_ 512
#define ZN_ 2048
#define NSLICE 128   // workgroups per step; each owns 4 hidden cols (16 z-cols)
#define KT_ 24       // K tiles of 32: 8 for x-part (E=256), 16 for h-part (H=512)

typedef short bf16x8 __attribute__((ext_vector_type(8)));
typedef float f32x4 __attribute__((ext_vector_type(4)));

__device__ __forceinline__ short f2bf(float f) {
  union { float f; unsigned u; } v; v.f = f;
  unsigned r = v.u + 0x7fffu + ((v.u >> 16) & 1u);
  return (short)(r >> 16);
}
__device__ __forceinline__ float sigmoidf_(float x) {
  return 1.f / (1.f + __expf(-x));
}
__device__ __forceinline__ float tanhf_(float x) {
  x = fminf(10.f, fmaxf(-10.f, x));
  float e = __expf(2.f * x);
  return (e - 1.f) / (e + 1.f);
}

// ---------------- phase 0: one-time prep ----------------

__global__ void k_emb_cvt(const float* __restrict__ emb, short* __restrict__ dst, int n8) {
  int i = blockIdx.x * blockDim.x + threadIdx.x;
  if (i >= n8) return;
  const float4* s = (const float4*)emb;
  float4 a = s[2 * i], b = s[2 * i + 1];
  bf16x8 o;
  o[0] = f2bf(a.x); o[1] = f2bf(a.y); o[2] = f2bf(a.z); o[3] = f2bf(a.w);
  o[4] = f2bf(b.x); o[5] = f2bf(b.y); o[6] = f2bf(b.z); o[7] = f2bf(b.w);
  ((bf16x8*)dst)[i] = o;
}

// Build MFMA B-fragment table: wf[(s*KT_+kt)*64 + lane] = 8 bf16, k = kt*32 + (lane>>4)*8 + i,
// zcol = g*H + s*4 + hc with c16 = lane&15, g = c16&3, hc = c16>>2.
__global__ void k_wfrag(const float* __restrict__ Wx, const float* __restrict__ Wh,
                        short* __restrict__ wf) {
  int tid = blockIdx.x * blockDim.x + threadIdx.x;
  if (tid >= NSLICE * KT_ * 64) return;
  int lane = tid & 63;
  int kt = (tid >> 6) % KT_;
  int s = tid / (64 * KT_);
  int c16 = lane & 15, ksub = lane >> 4;
  int g = c16 & 3, hc = c16 >> 2;
  int zcol = g * H_ + s * 4 + hc;
  int k0 = kt * 32 + ksub * 8;
  bf16x8 o;
#pragma unroll
  for (int i = 0; i < 8; ++i) {
    int k = k0 + i;
    float v = (k < E_) ? Wx[(size_t)k * ZN_ + zcol] : Wh[(size_t)(k - E_) * ZN_ + zcol];
    o[i] = f2bf(v);
  }
  ((bf16x8*)wf)[tid] = o;
}

__global__ void k_mask(const int* __restrict__ tok, unsigned long long* __restrict__ mask) {
  int t = blockIdx.x * blockDim.x + threadIdx.x;
  if (t >= T_) return;
  unsigned long long m = 0ull;
  for (int b = 0; b < B_; ++b)
    if (tok[b * T_ + t] != 0) m |= (1ull << b);
  mask[t] = m;
}

__global__ void k_init(const float* __restrict__ h0, const float* __restrict__ c0,
                       short* __restrict__ hbuf0, float* __restrict__ h_ws,
                       float* __restrict__ c_ws) {
  int i = blockIdx.x * blockDim.x + threadIdx.x;
  if (i >= B_ * H_) return;
  hbuf0[i] = f2bf(h0[i]);
  h_ws[i] = h0[i];
  c_ws[i] = c0[i];
}

// ---------------- per-timestep LSTM step ----------------
// grid = NSLICE WGs x 256 threads (4 waves, one 16-row M-tile each).
// z[64 x 16cols] = [x | h] @ [Wx ; Wh] (K=768, bf16 MFMA), gates, state update.

__global__ __launch_bounds__(256) void k_step(
    const int* __restrict__ tok, const short* __restrict__ emb,
    const short* __restrict__ wf, const float* __restrict__ bias,
    const unsigned long long* __restrict__ mask_ws,
    const short* __restrict__ hb_r, short* __restrict__ hb_w,
    float* __restrict__ c_ws, float* __restrict__ h_ws,
    float* __restrict__ out, int t)
{
  int s = blockIdx.x;
  int w = threadIdx.x >> 6, l = threadIdx.x & 63;
  int c16 = l & 15, ksub = l >> 4;
  int arow = w * 16 + c16;                 // A-fragment row (lane&15 within tile)
  int tk = tok[arow * T_ + t];
  const bf16x8* ax = (const bf16x8*)emb + (size_t)tk * 32 + ksub;   // +kt*4 per K-tile
  const bf16x8* ah = (const bf16x8*)hb_r + arow * 64 + ksub;        // +kt*4 per K-tile
  const bf16x8* bp = (const bf16x8*)wf + (size_t)s * KT_ * 64 + l;  // +kt*64 per K-tile

  f32x4 acc = {0.f, 0.f, 0.f, 0.f};
#pragma unroll
  for (int kt = 0; kt < 8; ++kt)
    acc = __builtin_amdgcn_mfma_f32_16x16x32_bf16(ax[kt * 4], bp[kt * 64], acc, 0, 0, 0);
#pragma unroll
  for (int kt = 0; kt < 16; ++kt)
    acc = __builtin_amdgcn_mfma_f32_16x16x32_bf16(ah[kt * 4], bp[(kt + 8) * 64], acc, 0, 0, 0);

  int g = c16 & 3, hc = c16 >> 2;
  float zb = bias[g * H_ + s * 4 + hc];

  // each lane activates its own gate (g==2 is the tanh gate)
  float act[4];
#pragma unroll
  for (int r = 0; r < 4; ++r) {
    float z = acc[r] + zb;
    act[r] = (g == 2) ? tanhf_(z) : sigmoidf_(z);
  }

  int base = l & ~3;                       // 4 gate-lanes of one hidden unit are adjacent
  unsigned long long mk = mask_ws[t];
#pragma unroll
  for (int r = 0; r < 4; ++r) {
    float fs = __shfl(act[r], base + 1);   // sigmoid(z_f)
    float gt = __shfl(act[r], base + 2);   // tanh(z_g)
    float os = __shfl(act[r], base + 3);   // sigmoid(z_o)
    if (g == 0) {                          // owner lane: act[r] = sigmoid(z_i)
      int row = w * 16 + ksub * 4 + r;     // D-fragment row mapping
      int col = s * 4 + hc;
      int st = row * H_ + col;
      float c_old = c_ws[st];
      float cn = fs * c_old + act[r] * gt;
      float hn = os * tanhf_(cn);
      bool mm = (mk >> row) & 1ull;
      float cwv = mm ? cn : c_old;
      float hwv = hn;
      if (!mm) hwv = h_ws[st];
      c_ws[st] = cwv;
      h_ws[st] = hwv;
      hb_w[st] = f2bf(hwv);
      out[((size_t)row * T_ + t) * H_ + col] = hwv;
      if (t == T_ - 1) {
        out[(size_t)B_ * T_ * H_ + st] = hwv;                 // h_T
        out[(size_t)B_ * T_ * H_ + B_ * H_ + st] = cwv;       // c_T
      }
    }
  }
}

// ---------------- launch ----------------

extern "C" void kernel_launch(void* const* d_in, const int* in_sizes, int n_in,
                              void* d_out, int out_size, void* d_ws, size_t ws_size,
                              hipStream_t stream) {
  (void)in_sizes; (void)n_in; (void)out_size; (void)ws_size;
  const int* tokens = (const int*)d_in[0];
  const float* h0 = (const float*)d_in[1];
  const float* c0 = (const float*)d_in[2];
  const float* emb = (const float*)d_in[3];
  const float* Wx = (const float*)d_in[4];
  const float* Wh = (const float*)d_in[5];
  const float* bias = (const float*)d_in[6];
  float* out = (float*)d_out;
  char* ws = (char*)d_ws;

  // ws layout (bytes): emb_bf16 16,384,000 | wfrag 3,145,728 | mask 8,192 |
  //                    hbuf x2 131,072 | c_ws 131,072 | h_ws 131,072  (~19.9 MB)
  short* emb_bf = (short*)(ws);
  short* wf     = (short*)(ws + 16384000);
  unsigned long long* mask = (unsigned long long*)(ws + 19529728);
  short* hb0    = (short*)(ws + 19537920);
  short* hb1    = (short*)(ws + 19537920 + 65536);
  float* c_ws   = (float*)(ws + 19668992);
  float* h_ws   = (float*)(ws + 19800064);

  k_emb_cvt<<<(1024000 + 255) / 256, 256, 0, stream>>>(emb, emb_bf, 1024000);
  k_wfrag<<<(NSLICE * KT_ * 64 + 255) / 256, 256, 0, stream>>>(Wx, Wh, wf);
  k_mask<<<(T_ + 255) / 256, 256, 0, stream>>>(tokens, mask);
  k_init<<<(B_ * H_ + 255) / 256, 256, 0, stream>>>(h0, c0, hb0, h_ws, c_ws);

  for (int t = 0; t < T_; ++t) {
    const short* hr = (t & 1) ? hb1 : hb0;
    short* hw       = (t & 1) ? hb0 : hb1;
    k_step<<<NSLICE, 256, 0, stream>>>(tokens, emb_bf, wf, bias, mask,
                                       hr, hw, c_ws, h_ws, out, t);
  }
}